// Round 8
// baseline (135.087 us; speedup 1.0000x reference)
//
#include <hip/hip_runtime.h>

// B=8, C=64, H=W=64, CI=32, N=4096 pixels, M=1024 pooled.
// y[b,n,:] = (a_n*S1[k_n,:] + S2[k_n,:])/1024 ; only W_w . y is needed, so
// track U = Ww.psi (64-dim) and its sorted-order prefixes T1/T2 directly.
// BN stats from per-k scalars (cnt, sum a, sum a^2) x T rows - no Gram.
//
// r13: FULL SPLIT -- 4 kernels, stream-ordered, NO in-kernel cross-block
// sync, NO sc1 anywhere. r12 proved kernel boundaries ~free while every
// in-kernel rendezvous cost 5-25us, and sc1 traffic defeats L2 (T[k][o]
// scatter inflated WRITE to 22MB via MALL sector writes + cross-XCD false
// sharing). All loads/stores are plain cached: L2 absorbs, end-of-kernel
// flush is once per kernel. T is now TRANSPOSED T[b][o][k]: each (b,o)
// column owned by one k3 block -> contiguous full-line stores; k4 reads
// strided but L2-cached (4.2MB total, high reuse). Keeps r12's wins:
// fused theta, U_T[b][o][m] coalesced, RK-based LDS scatter in P3.
// Numerics identical to r12 (absmax 0.03125 passed).
#define OFF_A    0         // a[b][n]               : 32768 floats
#define OFF_BB   32768     // bb[b][m]              : 8192
#define OFF_RK   40960     // rank[b][m] (int)      : 8192
#define OFF_U    57344     // U_T[b][o][m]          : 8*64*1024 = 524288
#define OFF_T1   581632    // T1[b][o][k<=1024]     : 8*64*1025 = 524800
#define OFF_T2   1106432   // T2[b][o][k]           : 524800
#define OFF_KK   1631232   // k[b][n] (int)         : 32768
#define OFF_MP1  1664000   // moment1 partials [b][o] : 512
#define OFF_MP2  1664512   // moment2 partials [b][o] : 512
#define OFF_HC   1665024   // hist cnt[b][1025]     : 8200
#define OFF_HS   1673224   // hist sum_a[b][1025]   : 8200
#define OFF_HS2  1681424   // hist sum_a2[b][1025]  : 8200

// k1 (= P1): phi/psi conv + 2x2 maxpool -> bb, U_T; theta -> a.
// 256 blocks x 1024 threads: block (b, sub) handles 32 pooled m's.
// Also zeroes this batch's hist slice (visible to k2 after boundary).
__global__ __launch_bounds__(1024) void k1(
    const float* __restrict__ x, const float* __restrict__ theta_w,
    const float* __restrict__ theta_b, const float* __restrict__ phi_w,
    const float* __restrict__ phi_b, const float* __restrict__ psi_w,
    const float* __restrict__ psi_b, const float* __restrict__ cp_w,
    const float* __restrict__ Ww, float* __restrict__ ws)
{
    __shared__ float sm[4160];    // 32 i-rows x 130: interleaved {phi,psi}
    __shared__ float sth[68];     // tw_eff[64] + tb_eff
    __shared__ float spsi[32*33]; // 32 m-rows x 32 i (pad 33)
    __shared__ float sWw[64*33];  // 64 o-rows x 32 i (pad 33)
    const int tid = threadIdx.x;
    const int bid = blockIdx.x;
    const int b   = bid >> 5;
    const int sub = bid & 31;

    // zero this block's slice of its batch's hist (3075 floats / 32 blocks)
    if (tid < 97) {
        int e = sub*97 + tid;
        if (e < 1025)      ws[OFF_HC  + b*1025 + e] = 0.0f;
        else if (e < 2050) ws[OFF_HS  + b*1025 + e - 1025] = 0.0f;
        else if (e < 3075) ws[OFF_HS2 + b*1025 + e - 2050] = 0.0f;
    }
    for (int e = tid; e < 2048; e += 1024) {
        int i = e >> 6, c = e & 63;
        sm[i*130 + 2*c]     = phi_w[e];
        sm[i*130 + 2*c + 1] = psi_w[e];
    }
    for (int e = tid; e < 2048; e += 1024)
        sWw[(e >> 5)*33 + (e & 31)] = Ww[(e >> 5)*33 + (e & 31)];
    if (tid < 64) {
        float s = 0;
        for (int i = 0; i < 32; ++i) s += cp_w[i]*theta_w[i*64 + tid];
        sth[tid] = s;
    } else if (tid == 64) {
        float s = 0;
        for (int i = 0; i < 32; ++i) s += cp_w[i]*theta_b[i];
        sth[64] = s;
    }
    __syncthreads();
    int i = tid & 31;
    int mIdx = tid >> 5;                 // 0..31
    int m = (sub << 5) + mIdx;
    int ph = m >> 5, pw = m & 31;
    const float* xb = x + b*262144 + ph*128 + pw*2;
    const float2* wrow = (const float2*)(sm + i*130);
    float tb = sth[64];
    float p0=0,p1=0,p2=0,p3=0,s0=0,s1=0,s2=0,s3=0;
    float a0=tb,a1=tb,a2=tb,a3=tb;       // theta: bias-first like before
    #pragma unroll 8
    for (int c = 0; c < 64; ++c) {
        float2 xa = *(const float2*)(xb + c*4096);
        float2 xc = *(const float2*)(xb + c*4096 + 64);
        float2 w  = wrow[c];             // {phi_w, psi_w}
        float st  = sth[c];              // broadcast read
        p0 += xa.x*w.x; p1 += xa.y*w.x; p2 += xc.x*w.x; p3 += xc.y*w.x;
        s0 += xa.x*w.y; s1 += xa.y*w.y; s2 += xc.x*w.y; s3 += xc.y*w.y;
        a0 += xa.x*st;  a1 += xa.y*st;  a2 += xc.x*st;  a3 += xc.y*st;
    }
    float pv = fmaxf(fmaxf(p0,p1), fmaxf(p2,p3)) + phi_b[i];
    float sv = fmaxf(fmaxf(s0,s1), fmaxf(s2,s3)) + psi_b[i];
    spsi[mIdx*33 + i] = sv;
    float v = pv * cp_w[32 + i];
    v += __shfl_xor(v, 16, 32);
    v += __shfl_xor(v,  8, 32);
    v += __shfl_xor(v,  4, 32);
    v += __shfl_xor(v,  2, 32);
    v += __shfl_xor(v,  1, 32);
    if (i == 0) {
        ws[OFF_BB + (b<<10) + m] = v;
        int nb = (b<<12) + ph*128 + pw*2;   // pixel (2ph,2pw)
        ws[OFF_A + nb]      = a0;
        ws[OFF_A + nb + 1]  = a1;
        ws[OFF_A + nb + 64] = a2;
        ws[OFF_A + nb + 65] = a3;
    }
    __syncthreads();
    // U-loop, o-major: 32 lanes (ml) store 128B contiguous per o
    #pragma unroll
    for (int rep = 0; rep < 2; ++rep) {
        int o  = (tid >> 5) + (rep << 5);   // 0..63
        int ml = tid & 31;
        const float* pr = &spsi[ml*33];     // 32 banks, 2-way: free
        const float* wr = &sWw[o*33];       // wave-uniform-ish: bcast
        float u = 0;
        #pragma unroll
        for (int i2 = 0; i2 < 32; ++i2) u += pr[i2]*wr[i2];
        ws[OFF_U + (((b<<6) + o)<<10) + (sub<<5) + ml] = u;
    }
}

// k2 (= P2): rank bb -> RK; k_n per pixel -> KK; per-batch histogram.
// 256 blocks x 1024 threads: block (b, sub).
__global__ __launch_bounds__(1024) void k2(float* __restrict__ ws)
{
    __shared__ float sb[1024];
    const int tid = threadIdx.x;
    const int b   = blockIdx.x >> 5;
    const int sub = blockIdx.x & 31;
    sb[tid] = ws[OFF_BB + (b<<10) + tid];
    __syncthreads();
    {   // rank 32 m's of this chunk (32 lanes per m, integer-exact)
        int ml = tid >> 5, jl = tid & 31;
        int m = (sub << 5) + ml;
        float vv = sb[m];
        int cnt = 0;
        for (int s = 0; s < 32; ++s) {
            int j = jl + (s << 5);
            float u = sb[j];
            cnt += (u > vv || (u == vv && j < m)) ? 1 : 0;
        }
        cnt += __shfl_xor(cnt,  1, 32);
        cnt += __shfl_xor(cnt,  2, 32);
        cnt += __shfl_xor(cnt,  4, 32);
        cnt += __shfl_xor(cnt,  8, 32);
        cnt += __shfl_xor(cnt, 16, 32);
        if (jl == 0)
            ((int*)ws)[OFF_RK + (b<<10) + m] = cnt;
    }
    {   // k_n for 128 pixels (8 lanes per pixel) + hist atomics
        int l = tid >> 3, jl = tid & 7;
        int n = (sub << 7) + l;
        float av = ws[OFF_A + (b<<12) + n];
        float tt = -av;
        const float2* sb2 = (const float2*)sb;
        int cnt = 0;
        for (int s = 0; s < 64; ++s) {
            float2 u = sb2[jl + (s << 3)];  // 8 distinct addrs: free
            cnt += (u.x > tt) ? 1 : 0;
            cnt += (u.y > tt) ? 1 : 0;
        }
        cnt += __shfl_xor(cnt, 1, 8);
        cnt += __shfl_xor(cnt, 2, 8);
        cnt += __shfl_xor(cnt, 4, 8);
        if (jl == 0) {
            ((int*)ws)[OFF_KK + (b<<12) + n] = cnt;
            atomicAdd(&ws[OFF_HC + b*1025 + cnt], 1.0f);
            atomicAdd(&ws[OFF_HS + b*1025 + cnt], av);
            atomicAdd(&ws[OFF_HS2 + b*1025 + cnt], av*av);
        }
    }
}

// k3 (= P3): sorted prefixes T1/T2 (k-major rows) + BN moment partials.
// 256 blocks x 1024 threads: block (b, og=sub), 2 output channels.
// U/BB/RK loads fully coalesced; sorted order via LDS scatter by rank.
__global__ __launch_bounds__(1024) void k3(float* __restrict__ ws)
{
    __shared__ float ssb[1024];
    __shared__ float sU0[1024];
    __shared__ float sU1[1024];
    __shared__ float shc[1025], shs[1025], shs2[1025];
    __shared__ float swp1[32], swp2[32];
    const int tid = threadIdx.x;
    const int b   = blockIdx.x >> 5;
    const int obase = (blockIdx.x & 31) << 1;
    {
        float bbv = ws[OFF_BB + (b<<10) + tid];
        int   rk  = ((const int*)ws)[OFF_RK + (b<<10) + tid];
        float u0  = ws[OFF_U + (((b<<6) + obase)<<10) + tid];
        float u1  = ws[OFF_U + (((b<<6) + obase + 1)<<10) + tid];
        ssb[rk] = bbv;
        sU0[rk] = u0;
        sU1[rk] = u1;
        shc[tid]  = ws[OFF_HC  + b*1025 + tid];
        shs[tid]  = ws[OFF_HS  + b*1025 + tid];
        shs2[tid] = ws[OFF_HS2 + b*1025 + tid];
        if (tid == 0) {
            shc[1024]  = ws[OFF_HC  + b*1025 + 1024];
            shs[1024]  = ws[OFF_HS  + b*1025 + 1024];
            shs2[1024] = ws[OFF_HS2 + b*1025 + 1024];
        }
    }
    __syncthreads();
    int ch = tid >> 1, o2 = tid & 1;            // 512 chunks x 2 o
    int o  = obase + o2;
    int wv = tid >> 6, chl = (tid & 63) >> 1;   // 32 chunks per wave
    const float* sU = o2 ? sU1 : sU0;
    float p[2], sp[2];
    float s1 = 0, s2 = 0;
    #pragma unroll
    for (int jl = 0; jl < 2; ++jl) {
        int jj = (ch<<1) + jl;
        float v = sU[jj];
        p[jl] = v;
        sp[jl] = ssb[jj]*v;
        s1 += v; s2 += sp[jl];
    }
    float own1 = s1, own2 = s2;
    #pragma unroll
    for (int d = 1; d < 32; d <<= 1) {
        float u1 = __shfl_up(s1, d<<1, 64);
        float u2 = __shfl_up(s2, d<<1, 64);
        if (chl >= d) { s1 += u1; s2 += u2; }
    }
    if (chl == 31) { swp1[(wv<<1)+o2] = s1; swp2[(wv<<1)+o2] = s2; }
    __syncthreads();
    float off1 = 0, off2 = 0;
    for (int w = 0; w < 16; ++w) {
        if (w < wv) { off1 += swp1[(w<<1)+o2]; off2 += swp2[(w<<1)+o2]; }
    }
    float run1 = off1 + s1 - own1;   // exclusive prefix before chunk ch
    float run2 = off2 + s2 - own2;
    float* T1 = ws + OFF_T1 + (((b<<6) + o)*1025);
    float* T2 = ws + OFF_T2 + (((b<<6) + o)*1025);
    if (ch == 0) { T1[0] = 0.0f; T2[0] = 0.0f; }   // k=0 row
    const float inv = 1.0f/1024.0f;
    float m1 = 0, m2 = 0;
    #pragma unroll
    for (int jl = 0; jl < 2; ++jl) {
        int k = (ch<<1) + jl + 1;
        run1 += p[jl]; run2 += sp[jl];
        float t1 = run1*inv, t2 = run2*inv;
        T1[k] = t1;                     // k-major: contiguous full lines
        T2[k] = t2;
        float c = shc[k], sa_ = shs[k], sa2 = shs2[k];
        m1 += sa_*t1 + c*t2;
        m2 += (sa2*t1 + 2.0f*sa_*t2)*t1 + c*t2*t2;
    }
    // reduce moments over chl (lane bits 1..5), keep o2 (bit 0)
    m1 += __shfl_xor(m1,  2, 64); m2 += __shfl_xor(m2,  2, 64);
    m1 += __shfl_xor(m1,  4, 64); m2 += __shfl_xor(m2,  4, 64);
    m1 += __shfl_xor(m1,  8, 64); m2 += __shfl_xor(m2,  8, 64);
    m1 += __shfl_xor(m1, 16, 64); m2 += __shfl_xor(m2, 16, 64);
    m1 += __shfl_xor(m1, 32, 64); m2 += __shfl_xor(m2, 32, 64);
    __syncthreads();   // swp reuse
    if (chl == 0) { swp1[(wv<<1)+o2] = m1; swp2[(wv<<1)+o2] = m2; }
    __syncthreads();
    if (tid < 2) {
        float a1 = 0, a2 = 0;
        for (int w = 0; w < 16; ++w) {
            a1 += swp1[(w<<1)+tid]; a2 += swp2[(w<<1)+tid];
        }
        ws[OFF_MP1 + (b<<6) + obase + tid] = a1;
        ws[OFF_MP2 + (b<<6) + obase + tid] = a2;
    }
}

// k4 (= P4): out[b,o,n] = A[o]*(a_n*T1[o,k_n]+T2[o,k_n]) + D[o] + x[b,o,n].
// 512 blocks x 512 threads (2 blocks/CU): block (b, n-group of 64).
__global__ __launch_bounds__(512) void k4(
    const float* __restrict__ x, const float* __restrict__ Wb,
    const float* __restrict__ gamma, const float* __restrict__ beta,
    const float* __restrict__ ws, float* __restrict__ out)
{
    __shared__ float tile[64*65];
    __shared__ float sa[64];
    __shared__ int   sk[64];
    __shared__ float sA[64];
    __shared__ float sD[64];
    const int tid = threadIdx.x;
    const int b   = blockIdx.x >> 6;
    const int n0  = (blockIdx.x & 63) << 6;
    if (tid < 64) {
        sa[tid] = ws[OFF_A + (b<<12) + n0 + tid];
        sk[tid] = ((const int*)ws)[OFF_KK + (b<<12) + n0 + tid];
        const float Ninv = 1.0f/32768.0f;
        float m1s = 0, m2s = 0;
        #pragma unroll
        for (int b3 = 0; b3 < 8; ++b3) {
            m1s += ws[OFF_MP1 + (b3<<6) + tid];
            m2s += ws[OFF_MP2 + (b3<<6) + tid];
        }
        float m1 = m1s * Ninv;
        float m2 = m2s * Ninv;
        float wb = Wb[tid];
        float mu  = m1 + wb;
        float E2  = m2 + 2.0f*wb*m1 + wb*wb;
        float var = E2 - mu*mu;
        float A = gamma[tid] * rsqrtf(var + 1e-5f);
        sA[tid] = A;
        sD[tid] = beta[tid] + A*(wb - mu);
    }
    __syncthreads();
    const float* T1 = ws + OFF_T1 + ((b<<6)*1025);
    const float* T2 = ws + OFF_T2 + ((b<<6)*1025);
    {
        int o = tid & 63, ng = tid >> 6;   // 8 groups x 8 n each
        float Ao = sA[o], Do = sD[o];
        const float* T1o = T1 + o*1025;
        const float* T2o = T2 + o*1025;
        #pragma unroll
        for (int j = 0; j < 8; ++j) {
            int n = (ng << 3) + j;
            int k = sk[n];                 // wave-uniform k; o-row L2-hot
            float a = sa[n];
            tile[o*65 + n] = Ao*(a*T1o[k] + T2o[k]) + Do;
        }
    }
    __syncthreads();
    {
        int n = tid & 63, og = tid >> 6;   // 8 groups x 8 o
        #pragma unroll
        for (int j = 0; j < 8; ++j) {
            int o = (og << 3) + j;
            int idx = ((b<<6) + o)*4096 + n0 + n;
            out[idx] = tile[o*65 + n] + x[idx];
        }
    }
}

extern "C" void kernel_launch(void* const* d_in, const int* in_sizes, int n_in,
                              void* d_out, int out_size, void* d_ws, size_t ws_size,
                              hipStream_t stream)
{
    const float* x       = (const float*)d_in[0];
    const float* theta_w = (const float*)d_in[1];
    const float* theta_b = (const float*)d_in[2];
    const float* phi_w   = (const float*)d_in[3];
    const float* phi_b   = (const float*)d_in[4];
    const float* psi_w   = (const float*)d_in[5];
    const float* psi_b   = (const float*)d_in[6];
    const float* cp_w    = (const float*)d_in[7];
    const float* Ww      = (const float*)d_in[8];
    const float* Wb      = (const float*)d_in[9];
    const float* gamma   = (const float*)d_in[10];
    const float* beta    = (const float*)d_in[11];
    float* ws  = (float*)d_ws;
    float* out = (float*)d_out;

    k1<<<256, 1024, 0, stream>>>(x, theta_w, theta_b, phi_w, phi_b,
                                 psi_w, psi_b, cp_w, Ww, ws);
    k2<<<256, 1024, 0, stream>>>(ws);
    k3<<<256, 1024, 0, stream>>>(ws);
    k4<<<512, 512, 0, stream>>>(x, Wb, gamma, beta, ws, out);
}

// Round 9
// 133.506 us; speedup vs baseline: 1.0118x; 1.0118x over previous
//
#include <hip/hip_runtime.h>

// B=8, C=64, H=W=64, CI=32, N=4096 pixels, M=1024 pooled.
// y[b,n,:] = (a_n*S1[k_n,:] + S2[k_n,:])/1024 ; only W_w . y is needed, so
// track U = Ww.psi (64-dim) and its sorted-order prefixes T1/T2 directly.
// BN stats from per-k scalars (cnt, sum a, sum a^2) x T rows - no Gram.
//
// r14: merge r7 + r8 winners. Structure = r7 (2 kernels, split ONLY at the
// global sync; per-batch tree barriers inside kA -- r8 proved kernel
// boundaries cost ~3-5us each, MORE than a per-batch barrier ~2-3us).
// Layout/store discipline = r8: T[b][o][k] k-major plain stores (each
// (b,o) column owned by one P3 block -> contiguous full lines; kills r7's
// 22.4MB sc1 sector-scatter), A/KK/MP plain stores (consumed only by kB
// across the boundary), A slice held in LDS from P1 to P2 (same block).
// sc1 retained ONLY for intra-kA cross-block data: bb, RK, U, hist.
#define OFF_A    0         // a[b][n]               : 32768 floats
#define OFF_BB   32768     // bb[b][m]              : 8192
#define OFF_RK   40960     // rank[b][m] (int)      : 8192
#define OFF_U    57344     // U_T[b][o][m]          : 8*64*1024 = 524288
#define OFF_T1   581632    // T1[b][o][k<=1024]     : 8*64*1025 = 524800
#define OFF_T2   1106432   // T2[b][o][k]           : 524800
#define OFF_KK   1631232   // k[b][n] (int)         : 32768
#define OFF_MP1  1664000   // moment1 partials [b][o] : 512
#define OFF_MP2  1664512   // moment2 partials [b][o] : 512
#define OFF_HC   1665024   // hist cnt[b][1025]     : 8200
#define OFF_HS   1673224   // hist sum_a[b][1025]   : 8200
#define OFF_HS2  1681424   // hist sum_a2[b][1025]  : 8200
#define OFF_BAR  1689624   // u32: batch b ctr @32*(b+1); flags @288,289

// Coherent (sc1, L2-bypass) helpers -- intra-kA cross-block data only.
__device__ __forceinline__ void stg(float* p, float v) {
    __hip_atomic_store(p, v, __ATOMIC_RELAXED, __HIP_MEMORY_SCOPE_AGENT);
}
__device__ __forceinline__ float ldg1(const float* p) {
    return __hip_atomic_load(p, __ATOMIC_RELAXED, __HIP_MEMORY_SCOPE_AGENT);
}
__device__ __forceinline__ void stgi(int* p, int v) {
    __hip_atomic_store(p, v, __ATOMIC_RELAXED, __HIP_MEMORY_SCOPE_AGENT);
}
__device__ __forceinline__ int ldgi(const int* p) {
    return __hip_atomic_load(p, __ATOMIC_RELAXED, __HIP_MEMORY_SCOPE_AGENT);
}
__device__ __forceinline__ void stgu(unsigned* p, unsigned v) {
    __hip_atomic_store(p, v, __ATOMIC_RELAXED, __HIP_MEMORY_SCOPE_AGENT);
}
__device__ __forceinline__ unsigned ldgu(const unsigned* p) {
    return __hip_atomic_load(p, __ATOMIC_RELAXED, __HIP_MEMORY_SCOPE_AGENT);
}

// kA LDS carve (floats), one 7524-float block (30.1 KB):
// P1: sm[0..4160) sth[4160..4228) spsi[4228..5284) sWw[5284..7396)
// P2: sb[0..1024)
// P3: ssb[0..1024) sU0[1024..2048) sU1[2048..3072) shc[3072..4097)
//     shs[4097..5122) shs2[5122..6147) swp1[6148..6180) swp2[6180..6212)
// persistent P1->P2: sA2[7396..7524) -- this block's 128 a-values
__global__ __launch_bounds__(1024) void kA(
    const float* __restrict__ x, const float* __restrict__ theta_w,
    const float* __restrict__ theta_b, const float* __restrict__ phi_w,
    const float* __restrict__ phi_b, const float* __restrict__ psi_w,
    const float* __restrict__ psi_b, const float* __restrict__ cp_w,
    const float* __restrict__ Ww, float* __restrict__ ws)
{
    __shared__ float sh[7524];
    const int tid = threadIdx.x;
    const int bid = blockIdx.x;
    const int b   = bid >> 5;     // 32 blocks per batch image
    const int sub = bid & 31;
    unsigned* bars = (unsigned*)(ws + OFF_BAR);
    float* sA2 = sh + 7396;

    // ---------- Phase 1: phi/psi conv+pool -> bb, U_T ; theta -> a --------
    {
        if (bid == 0 && tid == 0) {     // zero 8 batch counters (sc1)
            for (int i = 0; i < 8; ++i) stgu(&bars[(i + 1) << 5], 0u);
        }
        // zero this block's slice of ITS OWN batch's hist (sc1: target of
        // P2's MALL atomics); visible to batch peers at gen1.
        if (tid < 97) {
            int e = sub*97 + tid;
            if (e < 1025)      stg(&ws[OFF_HC  + b*1025 + e], 0.0f);
            else if (e < 2050) stg(&ws[OFF_HS  + b*1025 + e - 1025], 0.0f);
            else if (e < 3075) stg(&ws[OFF_HS2 + b*1025 + e - 2050], 0.0f);
        }
        float* sm   = sh;          // 32 i-rows x 130: interleaved {phi,psi}
        float* sth  = sh + 4160;   // tw_eff[64] + tb_eff
        float* spsi = sh + 4228;   // 32 m-rows x 32 i (pad 33)
        float* sWw  = sh + 5284;   // 64 o-rows x 32 i (pad 33)
        for (int e = tid; e < 2048; e += 1024) {
            int i = e >> 6, c = e & 63;
            sm[i*130 + 2*c]     = phi_w[e];
            sm[i*130 + 2*c + 1] = psi_w[e];
        }
        for (int e = tid; e < 2048; e += 1024)
            sWw[(e >> 5)*33 + (e & 31)] = Ww[(e >> 5)*33 + (e & 31)];
        if (tid < 64) {
            float s = 0;
            for (int i = 0; i < 32; ++i) s += cp_w[i]*theta_w[i*64 + tid];
            sth[tid] = s;
        } else if (tid == 64) {
            float s = 0;
            for (int i = 0; i < 32; ++i) s += cp_w[i]*theta_b[i];
            sth[64] = s;
        }
        __syncthreads();   // drains vmcnt -> block0's counter zeros at MALL
        if (bid == 0 && tid == 0) {    // publish ready flags (poison-proof)
            stgu(&bars[288], 0x5A5A5A5Au);
            stgu(&bars[289], 0xA5A5A5A5u);
        }
        int i = tid & 31;
        int mIdx = tid >> 5;                 // 0..31
        int m = (sub << 5) + mIdx;
        int ph = m >> 5, pw = m & 31;        // ph == sub
        const float* xb = x + b*262144 + ph*128 + pw*2;
        const float2* wrow = (const float2*)(sm + i*130);
        float tb = sth[64];
        float p0=0,p1=0,p2=0,p3=0,s0=0,s1=0,s2=0,s3=0;
        float a0=tb,a1=tb,a2=tb,a3=tb;       // theta: bias-first like before
        #pragma unroll 8
        for (int c = 0; c < 64; ++c) {
            float2 xa = *(const float2*)(xb + c*4096);
            float2 xc = *(const float2*)(xb + c*4096 + 64);
            float2 w  = wrow[c];             // {phi_w, psi_w}
            float st  = sth[c];              // broadcast read
            p0 += xa.x*w.x; p1 += xa.y*w.x; p2 += xc.x*w.x; p3 += xc.y*w.x;
            s0 += xa.x*w.y; s1 += xa.y*w.y; s2 += xc.x*w.y; s3 += xc.y*w.y;
            a0 += xa.x*st;  a1 += xa.y*st;  a2 += xc.x*st;  a3 += xc.y*st;
        }
        float pv = fmaxf(fmaxf(p0,p1), fmaxf(p2,p3)) + phi_b[i];
        float sv = fmaxf(fmaxf(s0,s1), fmaxf(s2,s3)) + psi_b[i];
        spsi[mIdx*33 + i] = sv;
        float v = pv * cp_w[32 + i];
        v += __shfl_xor(v, 16, 32);
        v += __shfl_xor(v,  8, 32);
        v += __shfl_xor(v,  4, 32);
        v += __shfl_xor(v,  2, 32);
        v += __shfl_xor(v,  1, 32);
        if (i == 0) {
            stg(&ws[OFF_BB + (b<<10) + m], v);   // sc1: read in P2/P3
            int nb = (b<<12) + ph*128 + pw*2;    // pixel (2ph,2pw)
            ws[OFF_A + nb]      = a0;            // plain: kB only
            ws[OFF_A + nb + 1]  = a1;
            ws[OFF_A + nb + 64] = a2;
            ws[OFF_A + nb + 65] = a3;
            int nl = pw*2;                       // local n (block's slice)
            sA2[nl]      = a0;                   // LDS: P2 reads these
            sA2[nl + 1]  = a1;
            sA2[nl + 64] = a2;
            sA2[nl + 65] = a3;
        }
        __syncthreads();
        // U-loop, o-major: 32 lanes (ml) store 128B contiguous per o (sc1)
        #pragma unroll
        for (int rep = 0; rep < 2; ++rep) {
            int o  = (tid >> 5) + (rep << 5);   // 0..63
            int ml = tid & 31;
            const float* pr = &spsi[ml*33];     // 32 banks, 2-way: free
            const float* wr = &sWw[o*33];       // wave-uniform-ish: bcast
            float u = 0;
            #pragma unroll
            for (int i2 = 0; i2 < 32; ++i2) u += pr[i2]*wr[i2];
            stg(&ws[OFF_U + (((b<<6) + o)<<10) + (sub<<5) + ml], u);
        }
    }
    // gen1 (per-batch), with one-time ready-flag check before first RMW
    __syncthreads();
    if (tid == 0) {
        while ((ldgu(&bars[288]) ^ ldgu(&bars[289])) != 0xFFFFFFFFu)
            __builtin_amdgcn_s_sleep(2);
        unsigned* ctr = bars + ((b + 1) << 5);
        __hip_atomic_fetch_add(ctr, 1u, __ATOMIC_RELAXED,
                               __HIP_MEMORY_SCOPE_AGENT);
        while (ldgu(ctr) < 32u) __builtin_amdgcn_s_sleep(2);
    }
    __syncthreads();

    // ---------- Phase 2: rank bb -> RK, k_n per pixel, per-b histogram ----
    {
        float* sb = sh;
        sb[tid] = ldg1(&ws[OFF_BB + (b<<10) + tid]);
        __syncthreads();
        {   // rank 32 m's of this chunk (32 lanes per m, integer-exact)
            int ml = tid >> 5, jl = tid & 31;
            int m = (sub << 5) + ml;
            float vv = sb[m];
            int cnt = 0;
            for (int s = 0; s < 32; ++s) {
                int j = jl + (s << 5);
                float u = sb[j];
                cnt += (u > vv || (u == vv && j < m)) ? 1 : 0;
            }
            cnt += __shfl_xor(cnt,  1, 32);
            cnt += __shfl_xor(cnt,  2, 32);
            cnt += __shfl_xor(cnt,  4, 32);
            cnt += __shfl_xor(cnt,  8, 32);
            cnt += __shfl_xor(cnt, 16, 32);
            if (jl == 0)
                stgi(&((int*)ws)[OFF_RK + (b<<10) + m], cnt);  // sc1: P3
        }
        {   // k_n for 128 pixels (8 lanes per pixel) + hist atomics
            int l = tid >> 3, jl = tid & 7;
            int n = (sub << 7) + l;
            float av = sA2[l];               // own block's P1 output (LDS)
            float tt = -av;
            const float2* sb2 = (const float2*)sb;
            int cnt = 0;
            for (int s = 0; s < 64; ++s) {
                float2 u = sb2[jl + (s << 3)];  // 8 distinct addrs: free
                cnt += (u.x > tt) ? 1 : 0;
                cnt += (u.y > tt) ? 1 : 0;
            }
            cnt += __shfl_xor(cnt, 1, 8);
            cnt += __shfl_xor(cnt, 2, 8);
            cnt += __shfl_xor(cnt, 4, 8);
            if (jl == 0) {
                ((int*)ws)[OFF_KK + (b<<12) + n] = cnt;  // plain: kB only
                atomicAdd(&ws[OFF_HC + b*1025 + cnt], 1.0f);
                atomicAdd(&ws[OFF_HS + b*1025 + cnt], av);
                atomicAdd(&ws[OFF_HS2 + b*1025 + cnt], av*av);
            }
        }
    }
    // gen2 (per-batch)
    __syncthreads();
    if (tid == 0) {
        unsigned* ctr = bars + ((b + 1) << 5);
        __hip_atomic_fetch_add(ctr, 1u, __ATOMIC_RELAXED,
                               __HIP_MEMORY_SCOPE_AGENT);
        while (ldgu(ctr) < 64u) __builtin_amdgcn_s_sleep(2);
    }
    __syncthreads();

    // ---------- Phase 3: sorted prefixes T1/T2 + BN moment partials ------
    // Block (b, og=sub): 2 output channels. sc1 loads (intra-kA data);
    // T k-major PLAIN stores (each (b,o) column owned by this block).
    {
        const int obase = sub << 1;
        float* ssb  = sh;           // sorted bb
        float* sU0  = sh + 1024;    // sorted U, o2=0
        float* sU1  = sh + 2048;    // sorted U, o2=1
        float* shc  = sh + 3072;
        float* shs  = sh + 4097;
        float* shs2 = sh + 5122;
        float* swp1 = sh + 6148;    // 32: per-(wave, o2) partials
        float* swp2 = sh + 6180;
        {
            float bbv = ldg1(&ws[OFF_BB + (b<<10) + tid]);
            int   rk  = ldgi(&((const int*)ws)[OFF_RK + (b<<10) + tid]);
            float u0  = ldg1(&ws[OFF_U + (((b<<6) + obase)<<10) + tid]);
            float u1  = ldg1(&ws[OFF_U + (((b<<6) + obase + 1)<<10) + tid]);
            ssb[rk] = bbv;
            sU0[rk] = u0;
            sU1[rk] = u1;
            shc[tid]  = ldg1(&ws[OFF_HC  + b*1025 + tid]);
            shs[tid]  = ldg1(&ws[OFF_HS  + b*1025 + tid]);
            shs2[tid] = ldg1(&ws[OFF_HS2 + b*1025 + tid]);
            if (tid == 0) {
                shc[1024]  = ldg1(&ws[OFF_HC  + b*1025 + 1024]);
                shs[1024]  = ldg1(&ws[OFF_HS  + b*1025 + 1024]);
                shs2[1024] = ldg1(&ws[OFF_HS2 + b*1025 + 1024]);
            }
        }
        __syncthreads();
        int ch = tid >> 1, o2 = tid & 1;            // 512 chunks x 2 o
        int o  = obase + o2;
        int wv = tid >> 6, chl = (tid & 63) >> 1;   // 32 chunks per wave
        const float* sU = o2 ? sU1 : sU0;
        float p[2], sp[2];
        float s1 = 0, s2 = 0;
        #pragma unroll
        for (int jl = 0; jl < 2; ++jl) {
            int jj = (ch<<1) + jl;
            float v = sU[jj];
            p[jl] = v;
            sp[jl] = ssb[jj]*v;
            s1 += v; s2 += sp[jl];
        }
        float own1 = s1, own2 = s2;
        #pragma unroll
        for (int d = 1; d < 32; d <<= 1) {
            float u1 = __shfl_up(s1, d<<1, 64);
            float u2 = __shfl_up(s2, d<<1, 64);
            if (chl >= d) { s1 += u1; s2 += u2; }
        }
        if (chl == 31) { swp1[(wv<<1)+o2] = s1; swp2[(wv<<1)+o2] = s2; }
        __syncthreads();
        float off1 = 0, off2 = 0;
        for (int w = 0; w < 16; ++w) {
            if (w < wv) { off1 += swp1[(w<<1)+o2]; off2 += swp2[(w<<1)+o2]; }
        }
        float run1 = off1 + s1 - own1;   // exclusive prefix before chunk ch
        float run2 = off2 + s2 - own2;
        float* T1 = ws + OFF_T1 + (((b<<6) + o)*1025);
        float* T2 = ws + OFF_T2 + (((b<<6) + o)*1025);
        if (ch == 0) { T1[0] = 0.0f; T2[0] = 0.0f; }   // k=0 row (plain)
        const float inv = 1.0f/1024.0f;
        float m1 = 0, m2 = 0;
        #pragma unroll
        for (int jl = 0; jl < 2; ++jl) {
            int k = (ch<<1) + jl + 1;
            run1 += p[jl]; run2 += sp[jl];
            float t1 = run1*inv, t2 = run2*inv;
            T1[k] = t1;                 // plain k-major: full-line stores
            T2[k] = t2;
            float c = shc[k], sa_ = shs[k], sa2 = shs2[k];
            m1 += sa_*t1 + c*t2;
            m2 += (sa2*t1 + 2.0f*sa_*t2)*t1 + c*t2*t2;
        }
        // reduce moments over chl (lane bits 1..5), keep o2 (bit 0)
        m1 += __shfl_xor(m1,  2, 64); m2 += __shfl_xor(m2,  2, 64);
        m1 += __shfl_xor(m1,  4, 64); m2 += __shfl_xor(m2,  4, 64);
        m1 += __shfl_xor(m1,  8, 64); m2 += __shfl_xor(m2,  8, 64);
        m1 += __shfl_xor(m1, 16, 64); m2 += __shfl_xor(m2, 16, 64);
        m1 += __shfl_xor(m1, 32, 64); m2 += __shfl_xor(m2, 32, 64);
        __syncthreads();   // swp reuse
        if (chl == 0) { swp1[(wv<<1)+o2] = m1; swp2[(wv<<1)+o2] = m2; }
        __syncthreads();
        if (tid < 2) {
            float a1 = 0, a2 = 0;
            for (int w = 0; w < 16; ++w) {
                a1 += swp1[(w<<1)+tid]; a2 += swp2[(w<<1)+tid];
            }
            ws[OFF_MP1 + (b<<6) + obase + tid] = a1;   // plain: kB only
            ws[OFF_MP2 + (b<<6) + obase + tid] = a2;
        }
    }
    // kernel ends: boundary flush publishes plain data; kB follows.
}

// kB (= P4): out[b,o,n] = A[o]*(a_n*T1[o,k_n]+T2[o,k_n]) + D[o] + x[b,o,n].
// 512 blocks x 512 threads (2 blocks/CU): block (b, n-group of 64).
// Plain cached loads: T (4.2MB, L2 reuse), A, KK, MP.
__global__ __launch_bounds__(512) void kB(
    const float* __restrict__ x, const float* __restrict__ Wb,
    const float* __restrict__ gamma, const float* __restrict__ beta,
    const float* __restrict__ ws, float* __restrict__ out)
{
    __shared__ float tile[64*65];
    __shared__ float sa[64];
    __shared__ int   sk[64];
    __shared__ float sA[64];
    __shared__ float sD[64];
    const int tid = threadIdx.x;
    const int b   = blockIdx.x >> 6;
    const int n0  = (blockIdx.x & 63) << 6;
    if (tid < 64) {
        sa[tid] = ws[OFF_A + (b<<12) + n0 + tid];
        sk[tid] = ((const int*)ws)[OFF_KK + (b<<12) + n0 + tid];
        const float Ninv = 1.0f/32768.0f;
        float m1s = 0, m2s = 0;
        #pragma unroll
        for (int b3 = 0; b3 < 8; ++b3) {
            m1s += ws[OFF_MP1 + (b3<<6) + tid];
            m2s += ws[OFF_MP2 + (b3<<6) + tid];
        }
        float m1 = m1s * Ninv;
        float m2 = m2s * Ninv;
        float wb = Wb[tid];
        float mu  = m1 + wb;
        float E2  = m2 + 2.0f*wb*m1 + wb*wb;
        float var = E2 - mu*mu;
        float A = gamma[tid] * rsqrtf(var + 1e-5f);
        sA[tid] = A;
        sD[tid] = beta[tid] + A*(wb - mu);
    }
    __syncthreads();
    const float* T1 = ws + OFF_T1 + ((b<<6)*1025);
    const float* T2 = ws + OFF_T2 + ((b<<6)*1025);
    {
        int o = tid & 63, ng = tid >> 6;   // 8 groups x 8 n each
        float Ao = sA[o], Do = sD[o];
        const float* T1o = T1 + o*1025;
        const float* T2o = T2 + o*1025;
        #pragma unroll
        for (int j = 0; j < 8; ++j) {
            int n = (ng << 3) + j;
            int k = sk[n];                 // wave-uniform k; o-row L2-hot
            float a = sa[n];
            tile[o*65 + n] = Ao*(a*T1o[k] + T2o[k]) + Do;
        }
    }
    __syncthreads();
    {
        int n = tid & 63, og = tid >> 6;   // 8 groups x 8 o
        #pragma unroll
        for (int j = 0; j < 8; ++j) {
            int o = (og << 3) + j;
            int idx = ((b<<6) + o)*4096 + n0 + n;
            out[idx] = tile[o*65 + n] + x[idx];
        }
    }
}

extern "C" void kernel_launch(void* const* d_in, const int* in_sizes, int n_in,
                              void* d_out, int out_size, void* d_ws, size_t ws_size,
                              hipStream_t stream)
{
    const float* x       = (const float*)d_in[0];
    const float* theta_w = (const float*)d_in[1];
    const float* theta_b = (const float*)d_in[2];
    const float* phi_w   = (const float*)d_in[3];
    const float* phi_b   = (const float*)d_in[4];
    const float* psi_w   = (const float*)d_in[5];
    const float* psi_b   = (const float*)d_in[6];
    const float* cp_w    = (const float*)d_in[7];
    const float* Ww      = (const float*)d_in[8];
    const float* Wb      = (const float*)d_in[9];
    const float* gamma   = (const float*)d_in[10];
    const float* beta    = (const float*)d_in[11];
    float* ws  = (float*)d_ws;
    float* out = (float*)d_out;

    kA<<<256, 1024, 0, stream>>>(x, theta_w, theta_b, phi_w, phi_b,
                                 psi_w, psi_b, cp_w, Ww, ws);
    kB<<<512, 512, 0, stream>>>(x, Wb, gamma, beta, ws, out);
}

// Round 10
// 125.620 us; speedup vs baseline: 1.0754x; 1.0628x over previous
//
#include <hip/hip_runtime.h>

// B=8, C=64, H=W=64, CI=32, N=4096 pixels, M=1024 pooled.
// y[b,n,:] = (a_n*S1[k_n,:] + S2[k_n,:])/1024 ; only W_w . y is needed, so
// track U = Ww.psi (64-dim) and its sorted-order prefixes T1/T2 directly.
// BN stats from per-k scalars (cnt, sum a, sum a^2) x T rows - no Gram.
//
// r15: r9 accounting closed -- kB was the hidden ~40us: k-major T made
// kB's gather read 64 distinct lines per wave-load (lane=o, stride 4.1KB).
// Fix: T back to o-major [b][k][o] so kB's load (wave-uniform k, lane=o)
// is one coalesced 256B line; P3 stores it with PLAIN stores (not r7's
// sc1 sector-scatter). Safety of partial-line plain writebacks across
// XCDs is PROVEN by r8/r9: MP1/MP2 has 8 blocks on different XCDs writing
// disjoint 8B of the same 64B line, and absmax stayed tight -> byte-
// granular dirty merge. Expected cost: kA WRITE +~10MB amplification
// (~2us HBM), kB -> ~6-10us. Everything else identical to r9.
#define OFF_A    0         // a[b][n]               : 32768 floats
#define OFF_BB   32768     // bb[b][m]              : 8192
#define OFF_RK   40960     // rank[b][m] (int)      : 8192
#define OFF_U    57344     // U_T[b][o][m]          : 8*64*1024 = 524288
#define OFF_T1   581632    // T1[b][k<=1024][o]     : 8*1025*64 = 524800
#define OFF_T2   1106432   // T2[b][k][o]           : 524800
#define OFF_KK   1631232   // k[b][n] (int)         : 32768
#define OFF_MP1  1664000   // moment1 partials [b][o] : 512
#define OFF_MP2  1664512   // moment2 partials [b][o] : 512
#define OFF_HC   1665024   // hist cnt[b][1025]     : 8200
#define OFF_HS   1673224   // hist sum_a[b][1025]   : 8200
#define OFF_HS2  1681424   // hist sum_a2[b][1025]  : 8200
#define OFF_BAR  1689624   // u32: batch b ctr @32*(b+1); flags @288,289

// Coherent (sc1, L2-bypass) helpers -- intra-kA cross-block data only.
__device__ __forceinline__ void stg(float* p, float v) {
    __hip_atomic_store(p, v, __ATOMIC_RELAXED, __HIP_MEMORY_SCOPE_AGENT);
}
__device__ __forceinline__ float ldg1(const float* p) {
    return __hip_atomic_load(p, __ATOMIC_RELAXED, __HIP_MEMORY_SCOPE_AGENT);
}
__device__ __forceinline__ void stgi(int* p, int v) {
    __hip_atomic_store(p, v, __ATOMIC_RELAXED, __HIP_MEMORY_SCOPE_AGENT);
}
__device__ __forceinline__ int ldgi(const int* p) {
    return __hip_atomic_load(p, __ATOMIC_RELAXED, __HIP_MEMORY_SCOPE_AGENT);
}
__device__ __forceinline__ void stgu(unsigned* p, unsigned v) {
    __hip_atomic_store(p, v, __ATOMIC_RELAXED, __HIP_MEMORY_SCOPE_AGENT);
}
__device__ __forceinline__ unsigned ldgu(const unsigned* p) {
    return __hip_atomic_load(p, __ATOMIC_RELAXED, __HIP_MEMORY_SCOPE_AGENT);
}

// kA LDS carve (floats), one 7524-float block (30.1 KB):
// P1: sm[0..4160) sth[4160..4228) spsi[4228..5284) sWw[5284..7396)
// P2: sb[0..1024)
// P3: ssb[0..1024) sU0[1024..2048) sU1[2048..3072) shc[3072..4097)
//     shs[4097..5122) shs2[5122..6147) swp1[6148..6180) swp2[6180..6212)
// persistent P1->P2: sA2[7396..7524) -- this block's 128 a-values
__global__ __launch_bounds__(1024) void kA(
    const float* __restrict__ x, const float* __restrict__ theta_w,
    const float* __restrict__ theta_b, const float* __restrict__ phi_w,
    const float* __restrict__ phi_b, const float* __restrict__ psi_w,
    const float* __restrict__ psi_b, const float* __restrict__ cp_w,
    const float* __restrict__ Ww, float* __restrict__ ws)
{
    __shared__ float sh[7524];
    const int tid = threadIdx.x;
    const int bid = blockIdx.x;
    const int b   = bid >> 5;     // 32 blocks per batch image
    const int sub = bid & 31;
    unsigned* bars = (unsigned*)(ws + OFF_BAR);
    float* sA2 = sh + 7396;

    // ---------- Phase 1: phi/psi conv+pool -> bb, U_T ; theta -> a --------
    {
        if (bid == 0 && tid == 0) {     // zero 8 batch counters (sc1)
            for (int i = 0; i < 8; ++i) stgu(&bars[(i + 1) << 5], 0u);
        }
        // zero this block's slice of ITS OWN batch's hist (sc1: target of
        // P2's MALL atomics); visible to batch peers at gen1.
        if (tid < 97) {
            int e = sub*97 + tid;
            if (e < 1025)      stg(&ws[OFF_HC  + b*1025 + e], 0.0f);
            else if (e < 2050) stg(&ws[OFF_HS  + b*1025 + e - 1025], 0.0f);
            else if (e < 3075) stg(&ws[OFF_HS2 + b*1025 + e - 2050], 0.0f);
        }
        float* sm   = sh;          // 32 i-rows x 130: interleaved {phi,psi}
        float* sth  = sh + 4160;   // tw_eff[64] + tb_eff
        float* spsi = sh + 4228;   // 32 m-rows x 32 i (pad 33)
        float* sWw  = sh + 5284;   // 64 o-rows x 32 i (pad 33)
        for (int e = tid; e < 2048; e += 1024) {
            int i = e >> 6, c = e & 63;
            sm[i*130 + 2*c]     = phi_w[e];
            sm[i*130 + 2*c + 1] = psi_w[e];
        }
        for (int e = tid; e < 2048; e += 1024)
            sWw[(e >> 5)*33 + (e & 31)] = Ww[(e >> 5)*33 + (e & 31)];
        if (tid < 64) {
            float s = 0;
            for (int i = 0; i < 32; ++i) s += cp_w[i]*theta_w[i*64 + tid];
            sth[tid] = s;
        } else if (tid == 64) {
            float s = 0;
            for (int i = 0; i < 32; ++i) s += cp_w[i]*theta_b[i];
            sth[64] = s;
        }
        __syncthreads();   // drains vmcnt -> block0's counter zeros at MALL
        if (bid == 0 && tid == 0) {    // publish ready flags (poison-proof)
            stgu(&bars[288], 0x5A5A5A5Au);
            stgu(&bars[289], 0xA5A5A5A5u);
        }
        int i = tid & 31;
        int mIdx = tid >> 5;                 // 0..31
        int m = (sub << 5) + mIdx;
        int ph = m >> 5, pw = m & 31;        // ph == sub
        const float* xb = x + b*262144 + ph*128 + pw*2;
        const float2* wrow = (const float2*)(sm + i*130);
        float tb = sth[64];
        float p0=0,p1=0,p2=0,p3=0,s0=0,s1=0,s2=0,s3=0;
        float a0=tb,a1=tb,a2=tb,a3=tb;       // theta: bias-first like before
        #pragma unroll 8
        for (int c = 0; c < 64; ++c) {
            float2 xa = *(const float2*)(xb + c*4096);
            float2 xc = *(const float2*)(xb + c*4096 + 64);
            float2 w  = wrow[c];             // {phi_w, psi_w}
            float st  = sth[c];              // broadcast read
            p0 += xa.x*w.x; p1 += xa.y*w.x; p2 += xc.x*w.x; p3 += xc.y*w.x;
            s0 += xa.x*w.y; s1 += xa.y*w.y; s2 += xc.x*w.y; s3 += xc.y*w.y;
            a0 += xa.x*st;  a1 += xa.y*st;  a2 += xc.x*st;  a3 += xc.y*st;
        }
        float pv = fmaxf(fmaxf(p0,p1), fmaxf(p2,p3)) + phi_b[i];
        float sv = fmaxf(fmaxf(s0,s1), fmaxf(s2,s3)) + psi_b[i];
        spsi[mIdx*33 + i] = sv;
        float v = pv * cp_w[32 + i];
        v += __shfl_xor(v, 16, 32);
        v += __shfl_xor(v,  8, 32);
        v += __shfl_xor(v,  4, 32);
        v += __shfl_xor(v,  2, 32);
        v += __shfl_xor(v,  1, 32);
        if (i == 0) {
            stg(&ws[OFF_BB + (b<<10) + m], v);   // sc1: read in P2/P3
            int nb = (b<<12) + ph*128 + pw*2;    // pixel (2ph,2pw)
            ws[OFF_A + nb]      = a0;            // plain: kB only
            ws[OFF_A + nb + 1]  = a1;
            ws[OFF_A + nb + 64] = a2;
            ws[OFF_A + nb + 65] = a3;
            int nl = pw*2;                       // local n (block's slice)
            sA2[nl]      = a0;                   // LDS: P2 reads these
            sA2[nl + 1]  = a1;
            sA2[nl + 64] = a2;
            sA2[nl + 65] = a3;
        }
        __syncthreads();
        // U-loop, o-major: 32 lanes (ml) store 128B contiguous per o (sc1)
        #pragma unroll
        for (int rep = 0; rep < 2; ++rep) {
            int o  = (tid >> 5) + (rep << 5);   // 0..63
            int ml = tid & 31;
            const float* pr = &spsi[ml*33];     // 32 banks, 2-way: free
            const float* wr = &sWw[o*33];       // wave-uniform-ish: bcast
            float u = 0;
            #pragma unroll
            for (int i2 = 0; i2 < 32; ++i2) u += pr[i2]*wr[i2];
            stg(&ws[OFF_U + (((b<<6) + o)<<10) + (sub<<5) + ml], u);
        }
    }
    // gen1 (per-batch), with one-time ready-flag check before first RMW
    __syncthreads();
    if (tid == 0) {
        while ((ldgu(&bars[288]) ^ ldgu(&bars[289])) != 0xFFFFFFFFu)
            __builtin_amdgcn_s_sleep(2);
        unsigned* ctr = bars + ((b + 1) << 5);
        __hip_atomic_fetch_add(ctr, 1u, __ATOMIC_RELAXED,
                               __HIP_MEMORY_SCOPE_AGENT);
        while (ldgu(ctr) < 32u) __builtin_amdgcn_s_sleep(2);
    }
    __syncthreads();

    // ---------- Phase 2: rank bb -> RK, k_n per pixel, per-b histogram ----
    {
        float* sb = sh;
        sb[tid] = ldg1(&ws[OFF_BB + (b<<10) + tid]);
        __syncthreads();
        {   // rank 32 m's of this chunk (32 lanes per m, integer-exact)
            int ml = tid >> 5, jl = tid & 31;
            int m = (sub << 5) + ml;
            float vv = sb[m];
            int cnt = 0;
            for (int s = 0; s < 32; ++s) {
                int j = jl + (s << 5);
                float u = sb[j];
                cnt += (u > vv || (u == vv && j < m)) ? 1 : 0;
            }
            cnt += __shfl_xor(cnt,  1, 32);
            cnt += __shfl_xor(cnt,  2, 32);
            cnt += __shfl_xor(cnt,  4, 32);
            cnt += __shfl_xor(cnt,  8, 32);
            cnt += __shfl_xor(cnt, 16, 32);
            if (jl == 0)
                stgi(&((int*)ws)[OFF_RK + (b<<10) + m], cnt);  // sc1: P3
        }
        {   // k_n for 128 pixels (8 lanes per pixel) + hist atomics
            int l = tid >> 3, jl = tid & 7;
            int n = (sub << 7) + l;
            float av = sA2[l];               // own block's P1 output (LDS)
            float tt = -av;
            const float2* sb2 = (const float2*)sb;
            int cnt = 0;
            for (int s = 0; s < 64; ++s) {
                float2 u = sb2[jl + (s << 3)];  // 8 distinct addrs: free
                cnt += (u.x > tt) ? 1 : 0;
                cnt += (u.y > tt) ? 1 : 0;
            }
            cnt += __shfl_xor(cnt, 1, 8);
            cnt += __shfl_xor(cnt, 2, 8);
            cnt += __shfl_xor(cnt, 4, 8);
            if (jl == 0) {
                ((int*)ws)[OFF_KK + (b<<12) + n] = cnt;  // plain: kB only
                atomicAdd(&ws[OFF_HC + b*1025 + cnt], 1.0f);
                atomicAdd(&ws[OFF_HS + b*1025 + cnt], av);
                atomicAdd(&ws[OFF_HS2 + b*1025 + cnt], av*av);
            }
        }
    }
    // gen2 (per-batch)
    __syncthreads();
    if (tid == 0) {
        unsigned* ctr = bars + ((b + 1) << 5);
        __hip_atomic_fetch_add(ctr, 1u, __ATOMIC_RELAXED,
                               __HIP_MEMORY_SCOPE_AGENT);
        while (ldgu(ctr) < 64u) __builtin_amdgcn_s_sleep(2);
    }
    __syncthreads();

    // ---------- Phase 3: sorted prefixes T1/T2 + BN moment partials ------
    // Block (b, og=sub): 2 output channels. sc1 loads (intra-kA data);
    // T o-major [b][k][o] PLAIN stores (byte-granular writeback merge
    // across XCDs proven safe by r8/r9 MP pattern).
    {
        const int obase = sub << 1;
        float* ssb  = sh;           // sorted bb
        float* sU0  = sh + 1024;    // sorted U, o2=0
        float* sU1  = sh + 2048;    // sorted U, o2=1
        float* shc  = sh + 3072;
        float* shs  = sh + 4097;
        float* shs2 = sh + 5122;
        float* swp1 = sh + 6148;    // 32: per-(wave, o2) partials
        float* swp2 = sh + 6180;
        {
            float bbv = ldg1(&ws[OFF_BB + (b<<10) + tid]);
            int   rk  = ldgi(&((const int*)ws)[OFF_RK + (b<<10) + tid]);
            float u0  = ldg1(&ws[OFF_U + (((b<<6) + obase)<<10) + tid]);
            float u1  = ldg1(&ws[OFF_U + (((b<<6) + obase + 1)<<10) + tid]);
            ssb[rk] = bbv;
            sU0[rk] = u0;
            sU1[rk] = u1;
            shc[tid]  = ldg1(&ws[OFF_HC  + b*1025 + tid]);
            shs[tid]  = ldg1(&ws[OFF_HS  + b*1025 + tid]);
            shs2[tid] = ldg1(&ws[OFF_HS2 + b*1025 + tid]);
            if (tid == 0) {
                shc[1024]  = ldg1(&ws[OFF_HC  + b*1025 + 1024]);
                shs[1024]  = ldg1(&ws[OFF_HS  + b*1025 + 1024]);
                shs2[1024] = ldg1(&ws[OFF_HS2 + b*1025 + 1024]);
            }
        }
        __syncthreads();
        int ch = tid >> 1, o2 = tid & 1;            // 512 chunks x 2 o
        int o  = obase + o2;
        int wv = tid >> 6, chl = (tid & 63) >> 1;   // 32 chunks per wave
        const float* sU = o2 ? sU1 : sU0;
        float p[2], sp[2];
        float s1 = 0, s2 = 0;
        #pragma unroll
        for (int jl = 0; jl < 2; ++jl) {
            int jj = (ch<<1) + jl;
            float v = sU[jj];
            p[jl] = v;
            sp[jl] = ssb[jj]*v;
            s1 += v; s2 += sp[jl];
        }
        float own1 = s1, own2 = s2;
        #pragma unroll
        for (int d = 1; d < 32; d <<= 1) {
            float u1 = __shfl_up(s1, d<<1, 64);
            float u2 = __shfl_up(s2, d<<1, 64);
            if (chl >= d) { s1 += u1; s2 += u2; }
        }
        if (chl == 31) { swp1[(wv<<1)+o2] = s1; swp2[(wv<<1)+o2] = s2; }
        __syncthreads();
        float off1 = 0, off2 = 0;
        for (int w = 0; w < 16; ++w) {
            if (w < wv) { off1 += swp1[(w<<1)+o2]; off2 += swp2[(w<<1)+o2]; }
        }
        float run1 = off1 + s1 - own1;   // exclusive prefix before chunk ch
        float run2 = off2 + s2 - own2;
        float* T1 = ws + OFF_T1 + b*65600;
        float* T2 = ws + OFF_T2 + b*65600;
        if (ch == 0) { T1[o] = 0.0f; T2[o] = 0.0f; }   // k=0 row (plain)
        const float inv = 1.0f/1024.0f;
        float m1 = 0, m2 = 0;
        #pragma unroll
        for (int jl = 0; jl < 2; ++jl) {
            int k = (ch<<1) + jl + 1;
            run1 += p[jl]; run2 += sp[jl];
            float t1 = run1*inv, t2 = run2*inv;
            T1[(k<<6) + o] = t1;        // plain o-major; L2 absorbs,
            T2[(k<<6) + o] = t2;        // byte-masked writeback at flush
            float c = shc[k], sa_ = shs[k], sa2 = shs2[k];
            m1 += sa_*t1 + c*t2;
            m2 += (sa2*t1 + 2.0f*sa_*t2)*t1 + c*t2*t2;
        }
        // reduce moments over chl (lane bits 1..5), keep o2 (bit 0)
        m1 += __shfl_xor(m1,  2, 64); m2 += __shfl_xor(m2,  2, 64);
        m1 += __shfl_xor(m1,  4, 64); m2 += __shfl_xor(m2,  4, 64);
        m1 += __shfl_xor(m1,  8, 64); m2 += __shfl_xor(m2,  8, 64);
        m1 += __shfl_xor(m1, 16, 64); m2 += __shfl_xor(m2, 16, 64);
        m1 += __shfl_xor(m1, 32, 64); m2 += __shfl_xor(m2, 32, 64);
        __syncthreads();   // swp reuse
        if (chl == 0) { swp1[(wv<<1)+o2] = m1; swp2[(wv<<1)+o2] = m2; }
        __syncthreads();
        if (tid < 2) {
            float a1 = 0, a2 = 0;
            for (int w = 0; w < 16; ++w) {
                a1 += swp1[(w<<1)+tid]; a2 += swp2[(w<<1)+tid];
            }
            ws[OFF_MP1 + (b<<6) + obase + tid] = a1;   // plain: kB only
            ws[OFF_MP2 + (b<<6) + obase + tid] = a2;
        }
    }
    // kernel ends: boundary flush publishes plain data; kB follows.
}

// kB (= P4): out[b,o,n] = A[o]*(a_n*T1[k_n,o]+T2[k_n,o]) + D[o] + x[b,o,n].
// 512 blocks x 512 threads (2 blocks/CU): block (b, n-group of 64).
// T gather: k wave-uniform, lane = o -> one coalesced 256B line per load.
__global__ __launch_bounds__(512) void kB(
    const float* __restrict__ x, const float* __restrict__ Wb,
    const float* __restrict__ gamma, const float* __restrict__ beta,
    const float* __restrict__ ws, float* __restrict__ out)
{
    __shared__ float tile[64*65];
    __shared__ float sa[64];
    __shared__ int   sk[64];
    __shared__ float sA[64];
    __shared__ float sD[64];
    const int tid = threadIdx.x;
    const int b   = blockIdx.x >> 6;
    const int n0  = (blockIdx.x & 63) << 6;
    if (tid < 64) {
        sa[tid] = ws[OFF_A + (b<<12) + n0 + tid];
        sk[tid] = ((const int*)ws)[OFF_KK + (b<<12) + n0 + tid];
        const float Ninv = 1.0f/32768.0f;
        float m1s = 0, m2s = 0;
        #pragma unroll
        for (int b3 = 0; b3 < 8; ++b3) {
            m1s += ws[OFF_MP1 + (b3<<6) + tid];
            m2s += ws[OFF_MP2 + (b3<<6) + tid];
        }
        float m1 = m1s * Ninv;
        float m2 = m2s * Ninv;
        float wb = Wb[tid];
        float mu  = m1 + wb;
        float E2  = m2 + 2.0f*wb*m1 + wb*wb;
        float var = E2 - mu*mu;
        float A = gamma[tid] * rsqrtf(var + 1e-5f);
        sA[tid] = A;
        sD[tid] = beta[tid] + A*(wb - mu);
    }
    __syncthreads();
    const float* T1 = ws + OFF_T1 + b*65600;
    const float* T2 = ws + OFF_T2 + b*65600;
    {
        int o = tid & 63, ng = tid >> 6;   // 8 waves x 8 n each
        float Ao = sA[o], Do = sD[o];
        #pragma unroll
        for (int j = 0; j < 8; ++j) {
            int n = (ng << 3) + j;
            int k = sk[n];                 // wave-uniform -> coalesced 256B
            float a = sa[n];
            float t1 = T1[(k<<6) + o];
            float t2 = T2[(k<<6) + o];
            tile[o*65 + n] = Ao*(a*t1 + t2) + Do;
        }
    }
    __syncthreads();
    {
        int n = tid & 63, og = tid >> 6;   // 8 groups x 8 o
        #pragma unroll
        for (int j = 0; j < 8; ++j) {
            int o = (og << 3) + j;
            int idx = ((b<<6) + o)*4096 + n0 + n;
            out[idx] = tile[o*65 + n] + x[idx];
        }
    }
}

extern "C" void kernel_launch(void* const* d_in, const int* in_sizes, int n_in,
                              void* d_out, int out_size, void* d_ws, size_t ws_size,
                              hipStream_t stream)
{
    const float* x       = (const float*)d_in[0];
    const float* theta_w = (const float*)d_in[1];
    const float* theta_b = (const float*)d_in[2];
    const float* phi_w   = (const float*)d_in[3];
    const float* phi_b   = (const float*)d_in[4];
    const float* psi_w   = (const float*)d_in[5];
    const float* psi_b   = (const float*)d_in[6];
    const float* cp_w    = (const float*)d_in[7];
    const float* Ww      = (const float*)d_in[8];
    const float* Wb      = (const float*)d_in[9];
    const float* gamma   = (const float*)d_in[10];
    const float* beta    = (const float*)d_in[11];
    float* ws  = (float*)d_ws;
    float* out = (float*)d_out;

    kA<<<256, 1024, 0, stream>>>(x, theta_w, theta_b, phi_w, phi_b,
                                 psi_w, psi_b, cp_w, Ww, ws);
    kB<<<512, 512, 0, stream>>>(x, Wb, gamma, beta, ws, out);
}